// Round 1
// baseline (168.027 us; speedup 1.0000x reference)
//
#include <hip/hip_runtime.h>
#include <hip/hip_bf16.h>

// USM sharpen: 48 images of 512x512 f32, 51-tap separable Gaussian, reflect pad.
// Pass 1: vblur(img) -> ws
// Pass 2: hblur(ws), residual = img - blur -> d_out   (d_out doubles as residual buffer)
// Pass 3: vblur(mask(residual)) -> ws                  (mask computed on the fly)
// Pass 4: hblur(ws) = soft_mask; final combine in-place on d_out

constexpr int H = 512, W = 512, NIMG = 48;
constexpr int K = 51, P = 25;
constexpr int VB = 16;          // outputs per thread, vertical pass
constexpr int HB = 8;           // outputs per lane, horizontal pass
constexpr int HROWS = 4;        // rows per block (1 wave per row), horizontal pass
constexpr int ROW_ELEMS = W + 2 * P;                       // 562 staged elements
constexpr int LDS_ROW = ROW_ELEMS + (ROW_ELEMS >> 5) + 1;  // swizzled size (579)

__device__ __forceinline__ int refl(int i, int n) {
    // jnp.pad 'reflect' (no edge repeat); P < n so one application suffices
    i = (i < 0) ? -i : i;
    i = (i >= n) ? (2 * n - 2 - i) : i;
    return i;
}

// +1 pad every 32 elements: stride-8 reads across 64 lanes cover all 32 banks (2-way alias = free)
__device__ __forceinline__ int swz(int i) { return i + (i >> 5); }

// MODE 0: plain vertical blur of src
// MODE 1: vertical blur of mask(src), mask = (|src|*255 > 10) ? 1 : 0
template <int MODE>
__global__ __launch_bounds__(256) void vblur_kern(const float* __restrict__ src,
                                                  float* __restrict__ dst,
                                                  const float* __restrict__ k1d) {
    const int x = blockIdx.x * 256 + threadIdx.x;
    const int y0 = blockIdx.y * VB;
    const size_t base = (size_t)blockIdx.z * (H * W);
    const float* s = src + base;
    float* d = dst + base;

    float kern[K];
#pragma unroll
    for (int k = 0; k < K; ++k) kern[k] = k1d[k];  // uniform address -> scalar loads

    float acc[VB];
#pragma unroll
    for (int o = 0; o < VB; ++o) acc[o] = 0.f;

    // register sliding window along y: 66 coalesced loads feed 16 outputs (816 FMA)
#pragma unroll
    for (int r = 0; r < VB + K - 1; ++r) {
        const int y = refl(y0 - P + r, H);
        float v = s[(size_t)y * W + x];
        if (MODE == 1) v = (fabsf(v) * 255.0f > 10.0f) ? 1.0f : 0.0f;
#pragma unroll
        for (int o = 0; o < VB; ++o) {
            const int k = r - o;
            if (0 <= k && k < K) acc[o] = fmaf(kern[k], v, acc[o]);
        }
    }

#pragma unroll
    for (int o = 0; o < VB; ++o) d[(size_t)(y0 + o) * W + x] = acc[o];
}

// MODE 0: dst = img - hblur(src)            (residual)
// MODE 1: sm = hblur(src); dst = sm*clip(img + 0.5*res, 0, 1) + (1-sm)*img
//         (res and dst may alias: per-thread same-index read-then-write only)
template <int MODE>
__global__ __launch_bounds__(256) void hblur_kern(const float* __restrict__ src,
                                                  const float* __restrict__ img,
                                                  const float* res,
                                                  float* dst,
                                                  const float* __restrict__ k1d) {
    __shared__ float lds[HROWS][LDS_ROW];
    const int wv = threadIdx.x >> 6;
    const int lane = threadIdx.x & 63;
    const long long row = (long long)blockIdx.x * HROWS + wv;  // 0 .. NIMG*H-1
    const float* s = src + (size_t)row * W;

    // stage one row (+reflected halos) per wave, swizzled
    for (int i = lane; i < ROW_ELEMS; i += 64)
        lds[wv][swz(i)] = s[refl(i - P, W)];
    __syncthreads();

    float kern[K];
#pragma unroll
    for (int k = 0; k < K; ++k) kern[k] = k1d[k];

    float acc[HB];
#pragma unroll
    for (int o = 0; o < HB; ++o) acc[o] = 0.f;

    const int xb = lane * HB;
    // register sliding window along x: 58 LDS reads feed 8 outputs (408 FMA)
#pragma unroll
    for (int r = 0; r < HB + K - 1; ++r) {
        const float v = lds[wv][swz(xb + r)];
#pragma unroll
        for (int o = 0; o < HB; ++o) {
            const int k = r - o;
            if (0 <= k && k < K) acc[o] = fmaf(kern[k], v, acc[o]);
        }
    }

    const size_t rowoff = (size_t)row * W + xb;
#pragma unroll
    for (int o = 0; o < HB; ++o) {
        const size_t idx = rowoff + o;
        const float iv = img[idx];
        if (MODE == 0) {
            dst[idx] = iv - acc[o];
        } else {
            const float rv = res[idx];
            const float sm = acc[o];
            float sharp = iv + 0.5f * rv;
            sharp = fminf(fmaxf(sharp, 0.f), 1.f);
            dst[idx] = sm * sharp + (1.f - sm) * iv;
        }
    }
}

extern "C" void kernel_launch(void* const* d_in, const int* in_sizes, int n_in,
                              void* d_out, int out_size, void* d_ws, size_t ws_size,
                              hipStream_t stream) {
    (void)in_sizes; (void)n_in; (void)out_size; (void)ws_size;
    const float* img = (const float*)d_in[0];
    const float* k1d = (const float*)d_in[1];
    float* out = (float*)d_out;
    float* tmp = (float*)d_ws;  // needs 48*512*512*4 = 50331648 B of scratch

    const dim3 vgrid(W / 256, H / VB, NIMG);  // (2, 32, 48)
    const dim3 hgrid((NIMG * H) / HROWS);     // 6144

    vblur_kern<0><<<vgrid, 256, 0, stream>>>(img, tmp, k1d);
    hblur_kern<0><<<hgrid, 256, 0, stream>>>(tmp, img, nullptr, out, k1d);  // out = residual
    vblur_kern<1><<<vgrid, 256, 0, stream>>>(out, tmp, k1d);                // tmp = vblur(mask)
    hblur_kern<1><<<hgrid, 256, 0, stream>>>(tmp, img, out, out, k1d);      // final, in-place
}